// Round 11
// baseline (177.235 us; speedup 1.0000x reference)
//
#include <hip/hip_runtime.h>

// N=100000 nodes, E=1600000 edges, D=64.
#define D_FEAT 64
#define E_BLK 2048           // edges per hist/partition tile -> ntiles = 782
#define MAXB 512             // max buckets (nb = ceil(N/256) = 391)
#define PADB 2048            // per-bucket pad slack in sorted_col (>= 256 rows * 7)

// Edge packing: (local_row << 24) | col   (col < 2^24, local_row < 256)
// hist_t layout:     [bucket * ntiles + tile]
// base_local layout: [tile * MAXB + bucket]
// sorted_col: per-bucket padded region starts at bucket_start + b*PADB; each
//   row's segment is padded to a multiple of 8 with the zero-row index n_nodes.

__device__ inline unsigned short f2bf(float f) {
    unsigned u = __float_as_uint(f);
    u += 0x7FFFu + ((u >> 16) & 1u);   // RNE
    return (unsigned short)(u >> 16);
}
__device__ inline float bf_lo(unsigned u) { return __uint_as_float(u << 16); }
__device__ inline float bf_hi(unsigned u) { return __uint_as_float(u & 0xFFFF0000u); }

// ---------------- K1: per-tile bucket histogram (+ optional bf16 conv) -----
// conv also writes one extra all-zero row at feat_bf[n_nodes*64 ..].
__global__ __launch_bounds__(256)
void hist_conv_kernel(const int* __restrict__ row, int* __restrict__ hist_t,
                      int n_edges, int nb, int ntiles,
                      const float* __restrict__ feat, unsigned short* __restrict__ feat_bf,
                      int n4) {
    int gb = blockIdx.x;
    int t = threadIdx.x;
    if (gb < ntiles) {
        __shared__ int h[MAXB];
        for (int i = t; i < MAXB; i += 256) h[i] = 0;
        __syncthreads();
        int e0 = gb * E_BLK, e1 = min(e0 + E_BLK, n_edges);
        for (int e = e0 + t; e < e1; e += 256)
            atomicAdd(&h[row[e] >> 8], 1);
        __syncthreads();
        for (int i = t; i < nb; i += 256)
            hist_t[(size_t)i * ntiles + gb] = h[i];
    } else {
        int i = (gb - ntiles) * 256 + t;
        if (i < n4) {
            float4 f = reinterpret_cast<const float4*>(feat)[i];
            ushort4 u;
            u.x = f2bf(f.x); u.y = f2bf(f.y); u.z = f2bf(f.z); u.w = f2bf(f.w);
            reinterpret_cast<ushort4*>(feat_bf)[i] = u;
        } else if (i < n4 + 16) {  // zero row (64 bf16 = 16 ushort4)
            reinterpret_cast<ushort4*>(feat_bf)[i] = make_ushort4(0, 0, 0, 0);
        }
    }
}

__global__ __launch_bounds__(256)
void tobf16_kernel(const float* __restrict__ feat, unsigned short* __restrict__ feat_bf,
                   int n4) {
    int i = blockIdx.x * 256 + threadIdx.x;
    if (i < n4) {
        float4 f = reinterpret_cast<const float4*>(feat)[i];
        ushort4 u;
        u.x = f2bf(f.x); u.y = f2bf(f.y); u.z = f2bf(f.z); u.w = f2bf(f.w);
        reinterpret_cast<ushort4*>(feat_bf)[i] = u;
    } else if (i < n4 + 16) {
        reinterpret_cast<ushort4*>(feat_bf)[i] = make_ushort4(0, 0, 0, 0);
    }
}

// ---------------- K2: per-bucket scan over tiles -> bases + totals ---------
__global__ __launch_bounds__(256)
void bases_kernel(const int* __restrict__ hist_t, int* __restrict__ base_local,
                  int* __restrict__ bucket_total, int ntiles) {
    __shared__ int s[256];
    int b = blockIdx.x;
    int t = threadIdx.x;
    const int* hp = hist_t + (size_t)b * ntiles;
    int v[4];
    int sum = 0;
    #pragma unroll
    for (int k = 0; k < 4; ++k) {
        int j = t * 4 + k;
        v[k] = (j < ntiles) ? hp[j] : 0;
        sum += v[k];
    }
    s[t] = sum;
    __syncthreads();
    for (int o = 1; o < 256; o <<= 1) {
        int x = (t >= o) ? s[t - o] : 0;
        __syncthreads();
        s[t] += x;
        __syncthreads();
    }
    int run = s[t] - sum;
    if (t == 255) bucket_total[b] = s[255];
    #pragma unroll
    for (int k = 0; k < 4; ++k) {
        int j = t * 4 + k;
        if (j < ntiles) base_local[(size_t)j * MAXB + b] = run;
        run += v[k];
    }
}

// ---------------- K3: partition (in-block bucket_off scan, LDS cursors) ----
__global__ __launch_bounds__(256)
void partition_kernel(const int* __restrict__ row, const int* __restrict__ col,
                      const int* __restrict__ bucket_total,
                      const int* __restrict__ base_local,
                      int* __restrict__ binned, int n_edges, int nb) {
    __shared__ int cur[MAXB];
    __shared__ int s[256];
    int t = threadIdx.x;
    int gb = blockIdx.x;
    int j0 = 2 * t, j1 = 2 * t + 1;
    int v0 = (j0 < nb) ? bucket_total[j0] : 0;
    int v1 = (j1 < nb) ? bucket_total[j1] : 0;
    int ps = v0 + v1;
    s[t] = ps;
    __syncthreads();
    for (int o = 1; o < 256; o <<= 1) {
        int x = (t >= o) ? s[t - o] : 0;
        __syncthreads();
        s[t] += x;
        __syncthreads();
    }
    int excl = s[t] - ps;
    cur[j0] = excl;
    cur[j1] = excl + v0;
    __syncthreads();
    const int* bl = base_local + (size_t)gb * MAXB;
    for (int i = t; i < nb; i += 256) cur[i] += bl[i];
    __syncthreads();
    int e0 = gb * E_BLK, e1 = min(e0 + E_BLK, n_edges);
    for (int e = e0 + t; e < e1; e += 256) {
        int r = row[e];
        int pos = atomicAdd(&cur[r >> 8], 1);
        binned[pos] = ((r & 255) << 24) | col[e];
    }
}

// ---------------- K4: per-bucket CSR with 8-padded rows --------------------
__global__ __launch_bounds__(256)
void csr_kernel(const int* __restrict__ binned, const int* __restrict__ bucket_total,
                int* __restrict__ offsets, int* __restrict__ degs,
                int* __restrict__ sorted_col,
                int n_nodes, int n_edges, int nb) {
    __shared__ int smem[1024];   // cnt[0..256) sc[256..512) cur[512..768) red[768..1024)
    int* cnt = smem;
    int* sc  = smem + 256;
    int* cur = smem + 512;
    int* red = smem + 768;
    int b = blockIdx.x;
    int t = threadIdx.x;
    // start (unpadded, into binned) = sum(bucket_total[0..b))
    int partial = 0;
    for (int j = t; j < b; j += 256) partial += bucket_total[j];
    red[t] = partial;
    __syncthreads();
    for (int o = 128; o > 0; o >>= 1) {
        if (t < o) red[t] += red[t + o];
        __syncthreads();
    }
    int start = red[0];
    int end = start + bucket_total[b];
    int pstart = start + b * PADB;      // padded region start in sorted_col

    int r0 = b << 8;
    cnt[t] = 0;
    __syncthreads();
    for (int i = start + t; i < end; i += 256)
        atomicAdd(&cnt[((unsigned)binned[i]) >> 24], 1);
    __syncthreads();
    int v = cnt[t];
    int pv = (v + 7) & ~7;              // padded row length
    sc[t] = pv;
    __syncthreads();
    for (int o = 1; o < 256; o <<= 1) {
        int x = (t >= o) ? sc[t - o] : 0;
        __syncthreads();
        sc[t] += x;
        __syncthreads();
    }
    int pexcl = sc[t] - pv;
    cur[t] = pexcl;
    int r = r0 + t;
    if (r < n_nodes) {
        offsets[r] = pstart + pexcl;
        degs[r] = v;
    }
    // pad fill: [v, pv) of this row's segment = zero-row index
    for (int k = v; k < pv; ++k)
        sorted_col[pstart + pexcl + k] = n_nodes;
    __syncthreads();
    for (int i = start + t; i < end; i += 256) {
        int pk = binned[i];
        int lr = ((unsigned)pk) >> 24;
        int pos = pstart + atomicAdd(&cur[lr], 1);
        sorted_col[pos] = pk & 0xFFFFFF;
    }
}

// ---------------- K5: one wave per row; branchless pipelined gather --------
__global__ __launch_bounds__(256)
void aggregate_kernel(const float* __restrict__ feat,
                      const unsigned short* __restrict__ feat_bf,
                      const int* __restrict__ offsets,
                      const int* __restrict__ degs,
                      const int* __restrict__ sorted_col,
                      float* __restrict__ out, int n_nodes) {
    int wave = (blockIdx.x * blockDim.x + threadIdx.x) >> 6;
    int lane = threadIdx.x & 63;
    if (wave >= n_nodes) return;
    int start = offsets[wave];
    int deg = degs[wave];
    int pdeg = (deg + 7) & ~7;
    int q = lane >> 3;      // 8 edge-groups
    int sub = lane & 7;     // 16B (8 bf16) slot within the 128B row

    float acc[8];
    #pragma unroll
    for (int k = 0; k < 8; ++k) acc[k] = 0.f;

    for (int base = 0; base < pdeg; base += 64) {
        int idx = base + lane;
        int colv = (idx < pdeg) ? sorted_col[start + idx] : n_nodes;
        int m = min(64, pdeg - base);   // multiple of 8
        int granules = m >> 3;
        int c = __shfl(colv, q, 64);
        uint4 d = *reinterpret_cast<const uint4*>(feat_bf + (size_t)c * D_FEAT + sub * 8);
        for (int g = 0; g < granules; ++g) {
            uint4 du = d;
            if (g + 1 < granules) {
                int cn = __shfl(colv, (g + 1) * 8 + q, 64);
                d = *reinterpret_cast<const uint4*>(
                    feat_bf + (size_t)cn * D_FEAT + sub * 8);
            }
            acc[0] += bf_lo(du.x); acc[1] += bf_hi(du.x);
            acc[2] += bf_lo(du.y); acc[3] += bf_hi(du.y);
            acc[4] += bf_lo(du.z); acc[5] += bf_hi(du.z);
            acc[6] += bf_lo(du.w); acc[7] += bf_hi(du.w);
        }
    }
    // fold the 8 edge-groups: lanes with same sub differ in bits 3..5
    #pragma unroll
    for (int k = 0; k < 8; ++k) {
        acc[k] += __shfl_xor(acc[k], 8, 64);
        acc[k] += __shfl_xor(acc[k], 16, 64);
        acc[k] += __shfl_xor(acc[k], 32, 64);
    }
    if (q == 0) {
        float inv = 1.0f / fmaxf((float)deg, 1.0f);
        size_t off = (size_t)wave * D_FEAT + sub * 8;
        const float4 f0 = *reinterpret_cast<const float4*>(feat + off);
        const float4 f1 = *reinterpret_cast<const float4*>(feat + off + 4);
        float4 o0, o1;
        o0.x = f0.x + acc[0] * inv;
        o0.y = f0.y + acc[1] * inv;
        o0.z = f0.z + acc[2] * inv;
        o0.w = f0.w + acc[3] * inv;
        o1.x = f1.x + acc[4] * inv;
        o1.y = f1.y + acc[5] * inv;
        o1.z = f1.z + acc[6] * inv;
        o1.w = f1.w + acc[7] * inv;
        *reinterpret_cast<float4*>(out + off) = o0;
        *reinterpret_cast<float4*>(out + off + 4) = o1;
    }
}

extern "C" void kernel_launch(void* const* d_in, const int* in_sizes, int n_in,
                              void* d_out, int out_size, void* d_ws, size_t ws_size,
                              hipStream_t stream) {
    const float* feat = (const float*)d_in[0];
    const int* row = (const int*)d_in[1];
    const int* col = (const int*)d_in[2];
    float* out = (float*)d_out;

    const int n_nodes = in_sizes[0] / D_FEAT;
    const int n_edges = in_sizes[1];
    const int nb = (n_nodes + 255) >> 8;                  // 391
    const int ntiles = (n_edges + E_BLK - 1) / E_BLK;     // 782
    const int n4 = n_nodes * D_FEAT / 4;                  // 1.6M float4s

    char* ws = (char*)d_ws;
    size_t bf_bytes     = (size_t)(n_nodes + 1) * D_FEAT * 2;   // +1 zero row
    size_t hist_bytes   = (size_t)nb * ntiles * 4;
    size_t base_bytes   = (size_t)ntiles * MAXB * 4;
    size_t binned_bytes = (size_t)n_edges * 4;
    size_t sorted_bytes = (size_t)(n_edges + nb * PADB + 64) * 4;  // padded
    size_t tail_bytes   = sorted_bytes
                        + (size_t)(n_nodes + 1) * 4       // offsets
                        + (size_t)(n_nodes + 1) * 4       // degs
                        + (size_t)nb * 4 + 128;           // bucket_total + pad

    size_t fat_need = bf_bytes + hist_bytes + base_bytes + binned_bytes + tail_bytes + 128;
    bool fat = (ws_size >= fat_need);

    unsigned short* feat_bf;
    int *binned, *hist_t, *base_local, *sorted_col, *offsets, *degs, *bucket_total;
    if (fat) {
        size_t p = 0;
        feat_bf    = (unsigned short*)(ws + p); p += (bf_bytes + 15) & ~(size_t)15;
        binned     = (int*)(ws + p); p += binned_bytes;
        hist_t     = (int*)(ws + p); p += hist_bytes;
        base_local = (int*)(ws + p); p += base_bytes;
        sorted_col = (int*)(ws + p); p += sorted_bytes;
        offsets    = (int*)(ws + p); p += (size_t)(n_nodes + 1) * 4;
        degs       = (int*)(ws + p); p += (size_t)(n_nodes + 1) * 4;
        bucket_total = (int*)(ws + p);
    } else {
        // Overlay: feat_bf shares {binned,hist_t,base_local}; conv runs after csr.
        size_t sort_bytes = binned_bytes + hist_bytes + base_bytes;
        size_t OV = (sort_bytes > bf_bytes ? sort_bytes : bf_bytes);
        OV = (OV + 15) & ~(size_t)15;
        feat_bf    = (unsigned short*)ws;
        binned     = (int*)ws;
        hist_t     = (int*)(ws + binned_bytes);
        base_local = (int*)(ws + binned_bytes + hist_bytes);
        size_t p = OV;
        sorted_col = (int*)(ws + p); p += sorted_bytes;
        offsets    = (int*)(ws + p); p += (size_t)(n_nodes + 1) * 4;
        degs       = (int*)(ws + p); p += (size_t)(n_nodes + 1) * 4;
        bucket_total = (int*)(ws + p);
    }

    {
        int conv_blocks = fat ? (n4 + 16 + 255) / 256 : 0;
        hist_conv_kernel<<<ntiles + conv_blocks, 256, 0, stream>>>(
            row, hist_t, n_edges, nb, ntiles, feat, feat_bf, n4);
    }
    bases_kernel<<<nb, 256, 0, stream>>>(hist_t, base_local, bucket_total, ntiles);
    partition_kernel<<<ntiles, 256, 0, stream>>>(row, col, bucket_total, base_local,
                                                 binned, n_edges, nb);
    csr_kernel<<<nb, 256, 0, stream>>>(binned, bucket_total, offsets, degs, sorted_col,
                                       n_nodes, n_edges, nb);
    if (!fat) {
        tobf16_kernel<<<(n4 + 16 + 255) / 256, 256, 0, stream>>>(feat, feat_bf, n4);
    }
    {
        long long total = (long long)n_nodes * 64;  // one wave per row
        int block = 256;
        int agrid = (int)((total + block - 1) / block);
        aggregate_kernel<<<agrid, block, 0, stream>>>(feat, feat_bf, offsets, degs,
                                                      sorted_col, out, n_nodes);
    }
}

// Round 12
// 171.517 us; speedup vs baseline: 1.0333x; 1.0333x over previous
//
#include <hip/hip_runtime.h>

// N=100000 nodes, E=1600000 edges, D=64.
#define D_FEAT 64
#define E_BLK 2048           // edges per hist/partition tile -> ntiles = 782
#define MAXB 512             // max buckets (nb = ceil(N/256) = 391)

// Edge packing: (local_row << 24) | col   (col < 2^24, local_row < 256)
// hist_t layout:     [bucket * ntiles + tile]
// base_local layout: [tile * MAXB + bucket]

__device__ inline unsigned short f2bf(float f) {
    unsigned u = __float_as_uint(f);
    u += 0x7FFFu + ((u >> 16) & 1u);   // RNE
    return (unsigned short)(u >> 16);
}
__device__ inline float bf_lo(unsigned u) { return __uint_as_float(u << 16); }
__device__ inline float bf_hi(unsigned u) { return __uint_as_float(u & 0xFFFF0000u); }

// ---------------- K1: per-tile bucket histogram (+ optional bf16 conv) -----
__global__ __launch_bounds__(256)
void hist_conv_kernel(const int* __restrict__ row, int* __restrict__ hist_t,
                      int n_edges, int nb, int ntiles,
                      const float* __restrict__ feat, unsigned short* __restrict__ feat_bf,
                      int n4) {
    int gb = blockIdx.x;
    int t = threadIdx.x;
    if (gb < ntiles) {
        __shared__ int h[MAXB];
        for (int i = t; i < MAXB; i += 256) h[i] = 0;
        __syncthreads();
        int e0 = gb * E_BLK, e1 = min(e0 + E_BLK, n_edges);
        for (int e = e0 + t; e < e1; e += 256)
            atomicAdd(&h[row[e] >> 8], 1);
        __syncthreads();
        for (int i = t; i < nb; i += 256)
            hist_t[(size_t)i * ntiles + gb] = h[i];
    } else {
        int i = (gb - ntiles) * 256 + t;
        if (i < n4) {
            float4 f = reinterpret_cast<const float4*>(feat)[i];
            ushort4 u;
            u.x = f2bf(f.x); u.y = f2bf(f.y); u.z = f2bf(f.z); u.w = f2bf(f.w);
            reinterpret_cast<ushort4*>(feat_bf)[i] = u;
        }
    }
}

__global__ __launch_bounds__(256)
void tobf16_kernel(const float* __restrict__ feat, unsigned short* __restrict__ feat_bf,
                   int n4) {
    int i = blockIdx.x * 256 + threadIdx.x;
    if (i >= n4) return;
    float4 f = reinterpret_cast<const float4*>(feat)[i];
    ushort4 u;
    u.x = f2bf(f.x); u.y = f2bf(f.y); u.z = f2bf(f.z); u.w = f2bf(f.w);
    reinterpret_cast<ushort4*>(feat_bf)[i] = u;
}

// ---------------- K2: per-bucket scan over tiles -> bases + totals ---------
__global__ __launch_bounds__(256)
void bases_kernel(const int* __restrict__ hist_t, int* __restrict__ base_local,
                  int* __restrict__ bucket_total, int ntiles) {
    __shared__ int s[256];
    int b = blockIdx.x;
    int t = threadIdx.x;
    const int* hp = hist_t + (size_t)b * ntiles;
    int v[4];
    int sum = 0;
    #pragma unroll
    for (int k = 0; k < 4; ++k) {
        int j = t * 4 + k;
        v[k] = (j < ntiles) ? hp[j] : 0;
        sum += v[k];
    }
    s[t] = sum;
    __syncthreads();
    for (int o = 1; o < 256; o <<= 1) {
        int x = (t >= o) ? s[t - o] : 0;
        __syncthreads();
        s[t] += x;
        __syncthreads();
    }
    int run = s[t] - sum;
    if (t == 255) bucket_total[b] = s[255];
    #pragma unroll
    for (int k = 0; k < 4; ++k) {
        int j = t * 4 + k;
        if (j < ntiles) base_local[(size_t)j * MAXB + b] = run;
        run += v[k];
    }
}

// ---------------- K3: partition (in-block bucket_off scan, LDS cursors) ----
__global__ __launch_bounds__(256)
void partition_kernel(const int* __restrict__ row, const int* __restrict__ col,
                      const int* __restrict__ bucket_total,
                      const int* __restrict__ base_local,
                      int* __restrict__ binned, int n_edges, int nb) {
    __shared__ int cur[MAXB];
    __shared__ int s[256];
    int t = threadIdx.x;
    int gb = blockIdx.x;
    int j0 = 2 * t, j1 = 2 * t + 1;
    int v0 = (j0 < nb) ? bucket_total[j0] : 0;
    int v1 = (j1 < nb) ? bucket_total[j1] : 0;
    int ps = v0 + v1;
    s[t] = ps;
    __syncthreads();
    for (int o = 1; o < 256; o <<= 1) {
        int x = (t >= o) ? s[t - o] : 0;
        __syncthreads();
        s[t] += x;
        __syncthreads();
    }
    int excl = s[t] - ps;
    cur[j0] = excl;
    cur[j1] = excl + v0;
    __syncthreads();
    const int* bl = base_local + (size_t)gb * MAXB;
    for (int i = t; i < nb; i += 256) cur[i] += bl[i];
    __syncthreads();
    int e0 = gb * E_BLK, e1 = min(e0 + E_BLK, n_edges);
    for (int e = e0 + t; e < e1; e += 256) {
        int r = row[e];
        int pos = atomicAdd(&cur[r >> 8], 1);
        binned[pos] = ((r & 255) << 24) | col[e];
    }
}

// ---------------- K4: per-bucket exact CSR (in-block start reduction) ------
__global__ __launch_bounds__(256)
void csr_kernel(const int* __restrict__ binned, const int* __restrict__ bucket_total,
                int* __restrict__ offsets, int* __restrict__ sorted_col,
                int n_nodes, int n_edges, int nb) {
    __shared__ int smem[1024];
    int* cnt = smem;
    int* sc  = smem + 256;
    int* cur = smem + 512;
    int* red = smem + 768;
    int b = blockIdx.x;
    int t = threadIdx.x;
    int partial = 0;
    for (int j = t; j < b; j += 256) partial += bucket_total[j];
    red[t] = partial;
    __syncthreads();
    for (int o = 128; o > 0; o >>= 1) {
        if (t < o) red[t] += red[t + o];
        __syncthreads();
    }
    int start = red[0];
    int end = start + bucket_total[b];

    int r0 = b << 8;
    cnt[t] = 0;
    __syncthreads();
    for (int i = start + t; i < end; i += 256)
        atomicAdd(&cnt[((unsigned)binned[i]) >> 24], 1);
    __syncthreads();
    int v = cnt[t];
    sc[t] = v;
    __syncthreads();
    for (int o = 1; o < 256; o <<= 1) {
        int x = (t >= o) ? sc[t - o] : 0;
        __syncthreads();
        sc[t] += x;
        __syncthreads();
    }
    int excl = sc[t] - v;
    cur[t] = excl;
    int r = r0 + t;
    if (r < n_nodes) offsets[r] = start + excl;
    if (b == 0 && t == 0) offsets[n_nodes] = n_edges;
    __syncthreads();
    for (int i = start + t; i < end; i += 256) {
        int pk = binned[i];
        int lr = ((unsigned)pk) >> 24;
        int pos = start + atomicAdd(&cur[lr], 1);
        sorted_col[pos] = pk & 0xFFFFFF;
    }
}

// ---------------- K5: one wave per TWO rows; 4 gather streams --------------
__global__ __launch_bounds__(256)
void aggregate_kernel(const float* __restrict__ feat,
                      const unsigned short* __restrict__ feat_bf,
                      const int* __restrict__ offsets,
                      const int* __restrict__ sorted_col,
                      float* __restrict__ out, int n_nodes) {
    int pair = (blockIdx.x * blockDim.x + threadIdx.x) >> 6;
    int lane = threadIdx.x & 63;
    int rA = pair * 2;
    if (rA >= n_nodes) return;
    int rB = rA + 1;
    bool hasB = (rB < n_nodes);
    int sA = offsets[rA];
    int eA = offsets[rA + 1];
    int sB = hasB ? offsets[rB] : 0;
    int eB = hasB ? offsets[rB + 1] : 0;
    int dA = eA - sA, dB = eB - sB;
    int q = lane >> 3;      // 8 edge-groups
    int sub = lane & 7;     // 16B (8 bf16) slot within the 128B row

    float a0[8], a1[8], b0[8], b1[8];
    #pragma unroll
    for (int k = 0; k < 8; ++k) { a0[k] = 0.f; a1[k] = 0.f; b0[k] = 0.f; b1[k] = 0.f; }

    int dmax = max(dA, dB);
    for (int base = 0; base < dmax; base += 64) {
        int iA = base + lane;
        int iB = base + lane;
        int colA = (iA < dA) ? sorted_col[sA + iA] : 0;
        int colB = (iB < dB) ? sorted_col[sB + iB] : 0;
        int mA = dA - base;                      // remaining for row A (may be <=0 or >64)
        int mB = dB - base;
        int rem = min(dmax - base, 64);
        int gmax = (rem + 7) >> 3;
        for (int g = 0; g < gmax; g += 2) {
            int j0 = (g << 3) + q;
            int j1 = ((g + 1) << 3) + q;
            int cA0 = __shfl(colA, j0, 64);
            int cA1 = __shfl(colA, j1, 64);
            int cB0 = __shfl(colB, j0, 64);
            int cB1 = __shfl(colB, j1, 64);
            if (j0 < mA) {
                uint4 d = *reinterpret_cast<const uint4*>(
                    feat_bf + (size_t)cA0 * D_FEAT + sub * 8);
                a0[0] += bf_lo(d.x); a0[1] += bf_hi(d.x);
                a0[2] += bf_lo(d.y); a0[3] += bf_hi(d.y);
                a0[4] += bf_lo(d.z); a0[5] += bf_hi(d.z);
                a0[6] += bf_lo(d.w); a0[7] += bf_hi(d.w);
            }
            if (j1 < mA) {
                uint4 d = *reinterpret_cast<const uint4*>(
                    feat_bf + (size_t)cA1 * D_FEAT + sub * 8);
                a1[0] += bf_lo(d.x); a1[1] += bf_hi(d.x);
                a1[2] += bf_lo(d.y); a1[3] += bf_hi(d.y);
                a1[4] += bf_lo(d.z); a1[5] += bf_hi(d.z);
                a1[6] += bf_lo(d.w); a1[7] += bf_hi(d.w);
            }
            if (j0 < mB) {
                uint4 d = *reinterpret_cast<const uint4*>(
                    feat_bf + (size_t)cB0 * D_FEAT + sub * 8);
                b0[0] += bf_lo(d.x); b0[1] += bf_hi(d.x);
                b0[2] += bf_lo(d.y); b0[3] += bf_hi(d.y);
                b0[4] += bf_lo(d.z); b0[5] += bf_hi(d.z);
                b0[6] += bf_lo(d.w); b0[7] += bf_hi(d.w);
            }
            if (j1 < mB) {
                uint4 d = *reinterpret_cast<const uint4*>(
                    feat_bf + (size_t)cB1 * D_FEAT + sub * 8);
                b1[0] += bf_lo(d.x); b1[1] += bf_hi(d.x);
                b1[2] += bf_lo(d.y); b1[3] += bf_hi(d.y);
                b1[4] += bf_lo(d.z); b1[5] += bf_hi(d.z);
                b1[6] += bf_lo(d.w); b1[7] += bf_hi(d.w);
            }
        }
    }
    #pragma unroll
    for (int k = 0; k < 8; ++k) { a0[k] += a1[k]; b0[k] += b1[k]; }
    // fold the 8 edge-groups: lanes with same sub differ in bits 3..5
    #pragma unroll
    for (int k = 0; k < 8; ++k) {
        a0[k] += __shfl_xor(a0[k], 8, 64);
        a0[k] += __shfl_xor(a0[k], 16, 64);
        a0[k] += __shfl_xor(a0[k], 32, 64);
        b0[k] += __shfl_xor(b0[k], 8, 64);
        b0[k] += __shfl_xor(b0[k], 16, 64);
        b0[k] += __shfl_xor(b0[k], 32, 64);
    }
    if (q == 0) {
        {
            float inv = 1.0f / fmaxf((float)dA, 1.0f);
            size_t off = (size_t)rA * D_FEAT + sub * 8;
            const float4 f0 = *reinterpret_cast<const float4*>(feat + off);
            const float4 f1 = *reinterpret_cast<const float4*>(feat + off + 4);
            float4 o0, o1;
            o0.x = f0.x + a0[0] * inv;
            o0.y = f0.y + a0[1] * inv;
            o0.z = f0.z + a0[2] * inv;
            o0.w = f0.w + a0[3] * inv;
            o1.x = f1.x + a0[4] * inv;
            o1.y = f1.y + a0[5] * inv;
            o1.z = f1.z + a0[6] * inv;
            o1.w = f1.w + a0[7] * inv;
            *reinterpret_cast<float4*>(out + off) = o0;
            *reinterpret_cast<float4*>(out + off + 4) = o1;
        }
        if (hasB) {
            float inv = 1.0f / fmaxf((float)dB, 1.0f);
            size_t off = (size_t)rB * D_FEAT + sub * 8;
            const float4 f0 = *reinterpret_cast<const float4*>(feat + off);
            const float4 f1 = *reinterpret_cast<const float4*>(feat + off + 4);
            float4 o0, o1;
            o0.x = f0.x + b0[0] * inv;
            o0.y = f0.y + b0[1] * inv;
            o0.z = f0.z + b0[2] * inv;
            o0.w = f0.w + b0[3] * inv;
            o1.x = f1.x + b0[4] * inv;
            o1.y = f1.y + b0[5] * inv;
            o1.z = f1.z + b0[6] * inv;
            o1.w = f1.w + b0[7] * inv;
            *reinterpret_cast<float4*>(out + off) = o0;
            *reinterpret_cast<float4*>(out + off + 4) = o1;
        }
    }
}

extern "C" void kernel_launch(void* const* d_in, const int* in_sizes, int n_in,
                              void* d_out, int out_size, void* d_ws, size_t ws_size,
                              hipStream_t stream) {
    const float* feat = (const float*)d_in[0];
    const int* row = (const int*)d_in[1];
    const int* col = (const int*)d_in[2];
    float* out = (float*)d_out;

    const int n_nodes = in_sizes[0] / D_FEAT;
    const int n_edges = in_sizes[1];
    const int nb = (n_nodes + 255) >> 8;                  // 391
    const int ntiles = (n_edges + E_BLK - 1) / E_BLK;     // 782
    const int n4 = n_nodes * D_FEAT / 4;                  // 1.6M float4s

    char* ws = (char*)d_ws;
    size_t bf_bytes     = (size_t)n_nodes * D_FEAT * 2;   // 12.8 MB
    size_t hist_bytes   = (size_t)nb * ntiles * 4;        // 1.22 MB
    size_t base_bytes   = (size_t)ntiles * MAXB * 4;      // 1.6 MB
    size_t binned_bytes = (size_t)n_edges * 4;            // 6.4 MB
    size_t tail_bytes   = (size_t)n_edges * 4
                        + (size_t)(n_nodes + 1) * 4
                        + (size_t)nb * 4 + 64;

    size_t fat_need = bf_bytes + hist_bytes + base_bytes + binned_bytes + tail_bytes + 64;
    bool fat = (ws_size >= fat_need);

    unsigned short* feat_bf;
    int *binned, *hist_t, *base_local, *sorted_col, *offsets, *bucket_total;
    if (fat) {
        size_t p = 0;
        feat_bf    = (unsigned short*)(ws + p); p += (bf_bytes + 15) & ~(size_t)15;
        binned     = (int*)(ws + p); p += binned_bytes;
        hist_t     = (int*)(ws + p); p += hist_bytes;
        base_local = (int*)(ws + p); p += base_bytes;
        sorted_col = (int*)(ws + p); p += (size_t)n_edges * 4;
        offsets    = (int*)(ws + p); p += (size_t)(n_nodes + 1) * 4;
        bucket_total = (int*)(ws + p);
    } else {
        size_t sort_bytes = binned_bytes + hist_bytes + base_bytes;
        size_t OV = (sort_bytes > bf_bytes ? sort_bytes : bf_bytes);
        OV = (OV + 15) & ~(size_t)15;
        feat_bf    = (unsigned short*)ws;
        binned     = (int*)ws;
        hist_t     = (int*)(ws + binned_bytes);
        base_local = (int*)(ws + binned_bytes + hist_bytes);
        size_t p = OV;
        sorted_col = (int*)(ws + p); p += (size_t)n_edges * 4;
        offsets    = (int*)(ws + p); p += (size_t)(n_nodes + 1) * 4;
        bucket_total = (int*)(ws + p);
    }

    {
        int conv_blocks = fat ? (n4 + 255) / 256 : 0;
        hist_conv_kernel<<<ntiles + conv_blocks, 256, 0, stream>>>(
            row, hist_t, n_edges, nb, ntiles, feat, feat_bf, n4);
    }
    bases_kernel<<<nb, 256, 0, stream>>>(hist_t, base_local, bucket_total, ntiles);
    partition_kernel<<<ntiles, 256, 0, stream>>>(row, col, bucket_total, base_local,
                                                 binned, n_edges, nb);
    csr_kernel<<<nb, 256, 0, stream>>>(binned, bucket_total, offsets, sorted_col,
                                       n_nodes, n_edges, nb);
    if (!fat) {
        tobf16_kernel<<<(n4 + 255) / 256, 256, 0, stream>>>(feat, feat_bf, n4);
    }
    {
        int pairs = (n_nodes + 1) / 2;                 // one wave per 2 rows
        long long total = (long long)pairs * 64;
        int block = 256;
        int agrid = (int)((total + block - 1) / block);
        aggregate_kernel<<<agrid, block, 0, stream>>>(feat, feat_bf, offsets, sorted_col,
                                                      out, n_nodes);
    }
}